// Round 1
// baseline (245.451 us; speedup 1.0000x reference)
//
#include <hip/hip_runtime.h>

typedef __attribute__((ext_vector_type(8))) short bf16x8;
typedef __attribute__((ext_vector_type(4))) float f32x4;

#define DEVFN static __device__ __forceinline__

DEVFN short f2bf(float f) {
  unsigned int u = __builtin_bit_cast(unsigned int, f);
  unsigned int r = (u + 0x7FFFu + ((u >> 16) & 1u)) >> 16;   // RNE
  return (short)r;
}

DEVFN f32x4 mfma_bf16(bf16x8 a, bf16x8 b, f32x4 c) {
  return __builtin_amdgcn_mfma_f32_16x16x32_bf16(a, b, c, 0, 0, 0);
}

DEVFN bf16x8 cvt8(const float* __restrict__ p) {
  const float4 u0 = *reinterpret_cast<const float4*>(p);
  const float4 u1 = *reinterpret_cast<const float4*>(p + 4);
  bf16x8 r;
  r[0] = f2bf(u0.x); r[1] = f2bf(u0.y); r[2] = f2bf(u0.z); r[3] = f2bf(u0.w);
  r[4] = f2bf(u1.x); r[5] = f2bf(u1.y); r[6] = f2bf(u1.z); r[7] = f2bf(u1.w);
  return r;
}

DEVFN f32x4 zero4() { f32x4 z = {0.f, 0.f, 0.f, 0.f}; return z; }
DEVFN bf16x8 zero8() { bf16x8 z = {0,0,0,0,0,0,0,0}; return z; }

// ---------------------------------------------------------------------------
// Kernel 1: kv = BN(x @ w_kv^T) -> bf16 (B*196, 384)
// grid = (100352/64) * 3 = 4704 blocks, 256 thr. Tile 64(M) x 128(N), K=256.
// ---------------------------------------------------------------------------
__global__ __launch_bounds__(256) void kv_gemm_k(
    const float* __restrict__ x, const float* __restrict__ w,
    const float* __restrict__ g, const float* __restrict__ bb,
    const float* __restrict__ m, const float* __restrict__ v,
    short* __restrict__ kv_out) {
  __shared__ float s_s[128], s_t[128];
  __shared__ short bs[128][40];   // B panel (128 ch x 32 k), padded stride
  const int tid = threadIdx.x;
  const int nt3 = blockIdx.x % 3;
  const int mt  = blockIdx.x / 3;
  if (tid < 128) {
    int ch = nt3 * 128 + tid;
    float sc = g[ch] * rsqrtf(v[ch] + 1e-5f);
    s_s[tid] = sc;
    s_t[tid] = bb[ch] - m[ch] * sc;
  }
  const int w_id = tid >> 6, lane = tid & 63;
  const int l15 = lane & 15, gq = lane >> 4;
  const int arow = mt * 64 + w_id * 16 + l15;
  const float* xrow = x + (size_t)arow * 256;

  f32x4 acc[8];
#pragma unroll
  for (int j = 0; j < 8; ++j) acc[j] = zero4();

  for (int c = 0; c < 8; ++c) {
    __syncthreads();
    // stage w[nt3*128 .. +128][c*32 .. +32] as bf16
    for (int i = tid; i < 4096; i += 256) {
      int row = i >> 5, kk = i & 31;
      bs[row][kk] = f2bf(w[(size_t)(nt3 * 128 + row) * 256 + c * 32 + kk]);
    }
    __syncthreads();
    bf16x8 a = cvt8(xrow + c * 32 + gq * 8);
#pragma unroll
    for (int j = 0; j < 8; ++j) {
      bf16x8 bj = *reinterpret_cast<const bf16x8*>(&bs[j * 16 + l15][gq * 8]);
      acc[j] = mfma_bf16(a, bj, acc[j]);
    }
  }
  const int orow = mt * 64 + w_id * 16 + gq * 4;
#pragma unroll
  for (int j = 0; j < 8; ++j) {
    int chl = j * 16 + l15;
    float sc = s_s[chl], tt = s_t[chl];
    int och = nt3 * 128 + chl;
#pragma unroll
    for (int r = 0; r < 4; ++r)
      kv_out[(size_t)(orow + r) * 384 + och] = f2bf(acc[j][r] * sc + tt);
  }
}

// ---------------------------------------------------------------------------
// Kernel 2: q = BN(xs @ w_q^T) -> bf16 (B*49, 128). grid = 392, 256 thr.
// ---------------------------------------------------------------------------
__global__ __launch_bounds__(256) void q_gemm_k(
    const float* __restrict__ x, const float* __restrict__ w,
    const float* __restrict__ g, const float* __restrict__ bb,
    const float* __restrict__ m, const float* __restrict__ v,
    short* __restrict__ q_out) {
  __shared__ float s_s[128], s_t[128];
  __shared__ short bs[128][40];
  const int tid = threadIdx.x;
  if (tid < 128) {
    float sc = g[tid] * rsqrtf(v[tid] + 1e-5f);
    s_s[tid] = sc;
    s_t[tid] = bb[tid] - m[tid] * sc;
  }
  const int mt = blockIdx.x;
  const int w_id = tid >> 6, lane = tid & 63;
  const int l15 = lane & 15, gq = lane >> 4;
  const int arow = mt * 64 + w_id * 16 + l15;
  const int b = arow / 49, qi = arow % 49;
  const int n = 28 * (qi / 7) + 2 * (qi % 7);   // strided subsample token
  const float* xrow = x + ((size_t)b * 196 + n) * 256;

  f32x4 acc[8];
#pragma unroll
  for (int j = 0; j < 8; ++j) acc[j] = zero4();

  for (int c = 0; c < 8; ++c) {
    __syncthreads();
    for (int i = tid; i < 4096; i += 256) {
      int row = i >> 5, kk = i & 31;
      bs[row][kk] = f2bf(w[(size_t)row * 256 + c * 32 + kk]);
    }
    __syncthreads();
    bf16x8 a = cvt8(xrow + c * 32 + gq * 8);
#pragma unroll
    for (int j = 0; j < 8; ++j) {
      bf16x8 bj = *reinterpret_cast<const bf16x8*>(&bs[j * 16 + l15][gq * 8]);
      acc[j] = mfma_bf16(a, bj, acc[j]);
    }
  }
  const int orow = mt * 64 + w_id * 16 + gq * 4;
#pragma unroll
  for (int j = 0; j < 8; ++j) {
    int ch = j * 16 + l15;
    float sc = s_s[ch], tt = s_t[ch];
#pragma unroll
    for (int r = 0; r < 4; ++r)
      q_out[(size_t)(orow + r) * 128 + ch] = f2bf(acc[j][r] * sc + tt);
  }
}

// ---------------------------------------------------------------------------
// Kernel 2b: ab_full[h][q][n] = ab_table[h][bias_idxs[q][n]]  (H*49 blocks)
// ---------------------------------------------------------------------------
__global__ void ab_gather_k(const float* __restrict__ tab,
                            const int* __restrict__ idxs,
                            float* __restrict__ out, int n_off) {
  const int hq = blockIdx.x;           // h*49 + q
  const int h = hq / 49, q = hq % 49;
  const int t = threadIdx.x;
  if (t < 196)
    out[(size_t)hq * 196 + t] = tab[h * n_off + idxs[q * 196 + t]];
}

// ---------------------------------------------------------------------------
// Kernel 3: per (b,h) attention. grid = 512*8 = 4096 blocks, 256 thr (4 waves).
// QK^T (K padded 16->32) -> bias -> softmax -> PV -> hardswish -> bf16 out.
// ---------------------------------------------------------------------------
__global__ __launch_bounds__(256) void attn_k(
    const short* __restrict__ kv, const short* __restrict__ qw,
    const float* __restrict__ ab, short* __restrict__ out) {
  __shared__ short vt[32][224];   // V^T : [d][token], zero-padded tokens>=196
  __shared__ short pl[64][224];   // P   : [qrow][token]
  const int b = blockIdx.x >> 3, h = blockIdx.x & 7;
  const int tid = threadIdx.x;

  // zero LDS (pad regions must be 0, not stale garbage)
  {
    unsigned int* z0 = reinterpret_cast<unsigned int*>(&vt[0][0]);
    for (int i = tid; i < 32 * 224 / 2; i += 256) z0[i] = 0u;
    unsigned int* z1 = reinterpret_cast<unsigned int*>(&pl[0][0]);
    for (int i = tid; i < 64 * 224 / 2; i += 256) z1[i] = 0u;
  }
  __syncthreads();

  const short* kvb = kv + ((size_t)b * 196) * 384 + h * 48;
  // stage V^T
  for (int i = tid; i < 196 * 32; i += 256) {
    int n = i >> 5, d = i & 31;
    vt[d][n] = kvb[(size_t)n * 384 + 16 + d];
  }

  const int w_id = tid >> 6, lane = tid & 63;
  const int l15 = lane & 15, gq = lane >> 4;

  // Q A-fragment (K dims 16..31 are zero padding)
  bf16x8 aq = zero8();
  const int qrow_a = w_id * 16 + l15;
  if (gq < 2 && qrow_a < 49)
    aq = *reinterpret_cast<const bf16x8*>(
        qw + ((size_t)b * 49 + qrow_a) * 128 + h * 16 + gq * 8);

  // S = q @ k^T  (13 n-tiles of 16 tokens)
  f32x4 s[13];
#pragma unroll
  for (int t = 0; t < 13; ++t) {
    bf16x8 bk = zero8();
    int n = t * 16 + l15;
    if (gq < 2 && n < 196)
      bk = *reinterpret_cast<const bf16x8*>(kvb + (size_t)n * 384 + gq * 8);
    s[t] = mfma_bf16(aq, bk, zero4());
  }

  // logits = s*SCALE + bias; mask n>=196
  const int qr = w_id * 16 + gq * 4;
#pragma unroll
  for (int t = 0; t < 13; ++t) {
    int n = t * 16 + l15;
#pragma unroll
    for (int r = 0; r < 4; ++r) {
      int q = qr + r;
      float val = -1e30f;
      if (n < 196) {
        float bias = (q < 49) ? ab[(size_t)(h * 49 + q) * 196 + n] : 0.f;
        val = s[t][r] * 0.25f + bias;
      }
      s[t][r] = val;
    }
  }

  // wave-parallel softmax per row (row spread over the 16 lanes of group gq)
  float inv[4];
#pragma unroll
  for (int r = 0; r < 4; ++r) {
    float mx = s[0][r];
#pragma unroll
    for (int t = 1; t < 13; ++t) mx = fmaxf(mx, s[t][r]);
#pragma unroll
    for (int k = 1; k < 16; k <<= 1) mx = fmaxf(mx, __shfl_xor(mx, k, 64));
    float sum = 0.f;
#pragma unroll
    for (int t = 0; t < 13; ++t) {
      float e = __expf(s[t][r] - mx);
      s[t][r] = e;
      sum += e;
    }
#pragma unroll
    for (int k = 1; k < 16; k <<= 1) sum += __shfl_xor(sum, k, 64);
    inv[r] = 1.f / sum;
  }

  // write P (bf16) to LDS, transposing C-layout -> row-major
#pragma unroll
  for (int t = 0; t < 13; ++t) {
    int n = t * 16 + l15;
#pragma unroll
    for (int r = 0; r < 4; ++r)
      pl[qr + r][n] = f2bf(s[t][r] * inv[r]);
  }
  __syncthreads();

  // PV: (64x224) @ (224x32), 7 K-chunks of 32
  f32x4 o[2];
  o[0] = zero4(); o[1] = zero4();
  for (int c = 0; c < 7; ++c) {
    bf16x8 ap = *reinterpret_cast<const bf16x8*>(&pl[w_id * 16 + l15][c * 32 + gq * 8]);
#pragma unroll
    for (int nt = 0; nt < 2; ++nt) {
      bf16x8 bv = *reinterpret_cast<const bf16x8*>(&vt[nt * 16 + l15][c * 32 + gq * 8]);
      o[nt] = mfma_bf16(ap, bv, o[nt]);
    }
  }

  // hardswish + store bf16 (B*49, 256) with channel = h*32 + d
#pragma unroll
  for (int nt = 0; nt < 2; ++nt) {
#pragma unroll
    for (int r = 0; r < 4; ++r) {
      int q = qr + r;
      if (q < 49) {
        float vv = o[nt][r];
        float hs = vv * fminf(fmaxf(vv + 3.f, 0.f), 6.f) * (1.f / 6.f);
        out[((size_t)b * 49 + q) * 256 + h * 32 + nt * 16 + l15] = f2bf(hs);
      }
    }
  }
}

// ---------------------------------------------------------------------------
// Kernel 4: out = BN(attn_out @ w_p^T) -> f32 (B*49, 512). grid = 392*4.
// ---------------------------------------------------------------------------
__global__ __launch_bounds__(256) void p_gemm_k(
    const short* __restrict__ a_in, const float* __restrict__ w,
    const float* __restrict__ g, const float* __restrict__ bb,
    const float* __restrict__ m, const float* __restrict__ v,
    float* __restrict__ out) {
  __shared__ float s_s[128], s_t[128];
  __shared__ short bs[128][40];
  const int tid = threadIdx.x;
  const int nt4 = blockIdx.x & 3;
  const int mt  = blockIdx.x >> 2;
  if (tid < 128) {
    int ch = nt4 * 128 + tid;
    float sc = g[ch] * rsqrtf(v[ch] + 1e-5f);
    s_s[tid] = sc;
    s_t[tid] = bb[ch] - m[ch] * sc;
  }
  const int w_id = tid >> 6, lane = tid & 63;
  const int l15 = lane & 15, gq = lane >> 4;
  const int arow = mt * 64 + w_id * 16 + l15;
  const short* arp = a_in + (size_t)arow * 256;

  f32x4 acc[8];
#pragma unroll
  for (int j = 0; j < 8; ++j) acc[j] = zero4();

  for (int c = 0; c < 8; ++c) {
    __syncthreads();
    for (int i = tid; i < 4096; i += 256) {
      int row = i >> 5, kk = i & 31;
      bs[row][kk] = f2bf(w[(size_t)(nt4 * 128 + row) * 256 + c * 32 + kk]);
    }
    __syncthreads();
    bf16x8 a = *reinterpret_cast<const bf16x8*>(arp + c * 32 + gq * 8);
#pragma unroll
    for (int j = 0; j < 8; ++j) {
      bf16x8 bj = *reinterpret_cast<const bf16x8*>(&bs[j * 16 + l15][gq * 8]);
      acc[j] = mfma_bf16(a, bj, acc[j]);
    }
  }
  const int orow = mt * 64 + w_id * 16 + gq * 4;
#pragma unroll
  for (int j = 0; j < 8; ++j) {
    int ch = j * 16 + l15;
    float sc = s_s[ch], tt = s_t[ch];
    int och = nt4 * 128 + ch;
#pragma unroll
    for (int r = 0; r < 4; ++r)
      out[(size_t)(orow + r) * 512 + och] = acc[j][r] * sc + tt;
  }
}

// ---------------------------------------------------------------------------
extern "C" void kernel_launch(void* const* d_in, const int* in_sizes, int n_in,
                              void* d_out, int out_size, void* d_ws, size_t ws_size,
                              hipStream_t stream) {
  const float* x    = (const float*)d_in[0];
  const float* w_kv = (const float*)d_in[1];
  const float* kv_g = (const float*)d_in[2];
  const float* kv_b = (const float*)d_in[3];
  const float* kv_m = (const float*)d_in[4];
  const float* kv_v = (const float*)d_in[5];
  const float* w_q  = (const float*)d_in[6];
  const float* q_g  = (const float*)d_in[7];
  const float* q_b  = (const float*)d_in[8];
  const float* q_m  = (const float*)d_in[9];
  const float* q_v  = (const float*)d_in[10];
  const float* w_p  = (const float*)d_in[11];
  const float* p_g  = (const float*)d_in[12];
  const float* p_b  = (const float*)d_in[13];
  const float* p_m  = (const float*)d_in[14];
  const float* p_v  = (const float*)d_in[15];
  const float* ab_t = (const float*)d_in[16];
  const int*   idxs = (const int*)d_in[17];
  const int n_off = in_sizes[16] / 8;

  char* ws = (char*)d_ws;
  short* kv_ws = (short*)(ws);                     // 512*196*384*2 = 77,070,336
  short* q_ws  = (short*)(ws + 77070336);          // 512*49*128*2  =  6,422,528
  short* at_ws = (short*)(ws + 83492864);          // 512*49*256*2  = 12,845,056
  float* ab_ws = (float*)(ws + 96337920);          // 8*49*196*4    =    307,328

  kv_gemm_k<<<dim3(4704), dim3(256), 0, stream>>>(x, w_kv, kv_g, kv_b, kv_m, kv_v, kv_ws);
  q_gemm_k<<<dim3(392), dim3(256), 0, stream>>>(x, w_q, q_g, q_b, q_m, q_v, q_ws);
  ab_gather_k<<<dim3(392), dim3(256), 0, stream>>>(ab_t, idxs, ab_ws, n_off);
  attn_k<<<dim3(4096), dim3(256), 0, stream>>>(kv_ws, q_ws, ab_ws, at_ws);
  p_gemm_k<<<dim3(1568), dim3(256), 0, stream>>>(at_ws, w_p, p_g, p_b, p_m, p_v, (float*)d_out);
}

// Round 2
// 192.554 us; speedup vs baseline: 1.2747x; 1.2747x over previous
//
#include <hip/hip_runtime.h>

typedef __attribute__((ext_vector_type(8))) short bf16x8;
typedef __attribute__((ext_vector_type(4))) float f32x4;

#define DEVFN static __device__ __forceinline__

DEVFN short f2bf(float f) {
  unsigned int u = __builtin_bit_cast(unsigned int, f);
  unsigned int r = (u + 0x7FFFu + ((u >> 16) & 1u)) >> 16;   // RNE
  return (short)r;
}

DEVFN f32x4 mfma_bf16(bf16x8 a, bf16x8 b, f32x4 c) {
  return __builtin_amdgcn_mfma_f32_16x16x32_bf16(a, b, c, 0, 0, 0);
}

DEVFN bf16x8 cvt8(const float* __restrict__ p) {
  const float4 u0 = *reinterpret_cast<const float4*>(p);
  const float4 u1 = *reinterpret_cast<const float4*>(p + 4);
  bf16x8 r;
  r[0] = f2bf(u0.x); r[1] = f2bf(u0.y); r[2] = f2bf(u0.z); r[3] = f2bf(u0.w);
  r[4] = f2bf(u1.x); r[5] = f2bf(u1.y); r[6] = f2bf(u1.z); r[7] = f2bf(u1.w);
  return r;
}

DEVFN f32x4 zero4() { f32x4 z = {0.f, 0.f, 0.f, 0.f}; return z; }
DEVFN bf16x8 zero8() { bf16x8 z = {0,0,0,0,0,0,0,0}; return z; }

DEVFN void gload_lds16(const void* g, void* l) {
  __builtin_amdgcn_global_load_lds(
      (const __attribute__((address_space(1))) unsigned int*)g,
      (__attribute__((address_space(3))) unsigned int*)l, 16, 0, 0);
}

// ---------------------------------------------------------------------------
// Weight pack: fold BN scale, cvt bf16, fragment-major layout
// pk[((c*(O/16)+j)*64+lane)*8+e] = w[j*16+(lane&15)][c*32+(lane>>4)*8+e]*s
// bias[o] = b[o] - m[o]*s[o]
// ---------------------------------------------------------------------------
__global__ void pack_w_k(const float* __restrict__ w, const float* __restrict__ g,
                         const float* __restrict__ b, const float* __restrict__ m,
                         const float* __restrict__ v, short* __restrict__ pk,
                         float* __restrict__ bias, int O) {
  const int t = blockIdx.x * 256 + threadIdx.x;
  const int nt = O >> 4;
  const int total = nt * 8 * 64;
  if (t < total) {
    int lane = t & 63;
    int j = (t >> 6) % nt;
    int c = (t >> 6) / nt;
    int row = j * 16 + (lane & 15);
    int col = c * 32 + (lane >> 4) * 8;
    float s = g[row] * rsqrtf(v[row] + 1e-5f);
    const float* wp = w + (size_t)row * 256 + col;
    short* o = pk + (size_t)t * 8;
#pragma unroll
    for (int e = 0; e < 8; ++e) o[e] = f2bf(wp[e] * s);
  }
  if (t < O) {
    float s = g[t] * rsqrtf(v[t] + 1e-5f);
    bias[t] = b[t] - m[t] * s;
  }
}

// ---------------------------------------------------------------------------
// Kernel 1: kv = x @ pk_kv + bias -> bf16 (B*196, 384)
// grid = 100352/64 = 1568 blocks, 256 thr. Tile 64(M) x 384(N full), K=256.
// ---------------------------------------------------------------------------
__global__ __launch_bounds__(256) void kv_gemm2(
    const float* __restrict__ x, const short* __restrict__ pk,
    const float* __restrict__ bias, short* __restrict__ out) {
  __shared__ short bs[24 * 512];   // 24 KB: [j][lane][8]
  __shared__ float sb[384];
  const int tid = threadIdx.x, w_id = tid >> 6, lane = tid & 63;
  const int l15 = lane & 15, gq = lane >> 4;
  const int mt = blockIdx.x;
  for (int i = tid; i < 384; i += 256) sb[i] = bias[i];
  const int arow = mt * 64 + w_id * 16 + l15;
  const float* xrow = x + (size_t)arow * 256;

  f32x4 acc[24];
#pragma unroll
  for (int j = 0; j < 24; ++j) acc[j] = zero4();

  for (int c = 0; c < 8; ++c) {
    for (int seg = w_id; seg < 24; seg += 4)
      gload_lds16(pk + ((size_t)(c * 24 + seg) * 64 + lane) * 8, &bs[seg * 512]);
    bf16x8 a = cvt8(xrow + c * 32 + gq * 8);
    __syncthreads();   // drains vmcnt -> staged data visible
#pragma unroll
    for (int j = 0; j < 24; ++j) {
      bf16x8 bj = *reinterpret_cast<const bf16x8*>(&bs[(j * 64 + lane) * 8]);
      acc[j] = mfma_bf16(a, bj, acc[j]);
    }
    __syncthreads();   // protect LDS overwrite
  }
  const int orow = mt * 64 + w_id * 16 + gq * 4;
#pragma unroll
  for (int j = 0; j < 24; ++j) {
    int och = j * 16 + l15;
    float bb = sb[och];
#pragma unroll
    for (int r = 0; r < 4; ++r)
      out[(size_t)(orow + r) * 384 + och] = f2bf(acc[j][r] + bb);
  }
}

// ---------------------------------------------------------------------------
// Kernel 2: q = xs @ pk_q + bias -> bf16 (B*49, 128). grid = 392.
// ---------------------------------------------------------------------------
__global__ __launch_bounds__(256) void q_gemm2(
    const float* __restrict__ x, const short* __restrict__ pk,
    const float* __restrict__ bias, short* __restrict__ out) {
  __shared__ short bs[8 * 512];
  __shared__ float sb[128];
  const int tid = threadIdx.x, w_id = tid >> 6, lane = tid & 63;
  const int l15 = lane & 15, gq = lane >> 4;
  const int mt = blockIdx.x;
  if (tid < 128) sb[tid] = bias[tid];
  const int arow = mt * 64 + w_id * 16 + l15;
  const int b = arow / 49, qi = arow % 49;
  const int n = 28 * (qi / 7) + 2 * (qi % 7);
  const float* xrow = x + ((size_t)b * 196 + n) * 256;

  f32x4 acc[8];
#pragma unroll
  for (int j = 0; j < 8; ++j) acc[j] = zero4();

  for (int c = 0; c < 8; ++c) {
    for (int seg = w_id; seg < 8; seg += 4)
      gload_lds16(pk + ((size_t)(c * 8 + seg) * 64 + lane) * 8, &bs[seg * 512]);
    bf16x8 a = cvt8(xrow + c * 32 + gq * 8);
    __syncthreads();
#pragma unroll
    for (int j = 0; j < 8; ++j) {
      bf16x8 bj = *reinterpret_cast<const bf16x8*>(&bs[(j * 64 + lane) * 8]);
      acc[j] = mfma_bf16(a, bj, acc[j]);
    }
    __syncthreads();
  }
  const int orow = mt * 64 + w_id * 16 + gq * 4;
#pragma unroll
  for (int j = 0; j < 8; ++j) {
    int ch = j * 16 + l15;
    float bb = sb[ch];
#pragma unroll
    for (int r = 0; r < 4; ++r)
      out[(size_t)(orow + r) * 128 + ch] = f2bf(acc[j][r] + bb);
  }
}

// ---------------------------------------------------------------------------
// Kernel 2b: ab_full[h][q][n] = ab_table[h][bias_idxs[q][n]]
// ---------------------------------------------------------------------------
__global__ void ab_gather_k(const float* __restrict__ tab,
                            const int* __restrict__ idxs,
                            float* __restrict__ out, int n_off) {
  const int hq = blockIdx.x;
  const int h = hq / 49, q = hq % 49;
  const int t = threadIdx.x;
  if (t < 196)
    out[(size_t)hq * 196 + t] = tab[h * n_off + idxs[q * 196 + t]];
}

// ---------------------------------------------------------------------------
// Kernel 3: per (b,h) attention (unchanged from R1).
// ---------------------------------------------------------------------------
__global__ __launch_bounds__(256) void attn_k(
    const short* __restrict__ kv, const short* __restrict__ qw,
    const float* __restrict__ ab, short* __restrict__ out) {
  __shared__ short vt[32][224];
  __shared__ short pl[64][224];
  const int b = blockIdx.x >> 3, h = blockIdx.x & 7;
  const int tid = threadIdx.x;

  {
    unsigned int* z0 = reinterpret_cast<unsigned int*>(&vt[0][0]);
    for (int i = tid; i < 32 * 224 / 2; i += 256) z0[i] = 0u;
    unsigned int* z1 = reinterpret_cast<unsigned int*>(&pl[0][0]);
    for (int i = tid; i < 64 * 224 / 2; i += 256) z1[i] = 0u;
  }
  __syncthreads();

  const short* kvb = kv + ((size_t)b * 196) * 384 + h * 48;
  for (int i = tid; i < 196 * 32; i += 256) {
    int n = i >> 5, d = i & 31;
    vt[d][n] = kvb[(size_t)n * 384 + 16 + d];
  }

  const int w_id = tid >> 6, lane = tid & 63;
  const int l15 = lane & 15, gq = lane >> 4;

  bf16x8 aq = zero8();
  const int qrow_a = w_id * 16 + l15;
  if (gq < 2 && qrow_a < 49)
    aq = *reinterpret_cast<const bf16x8*>(
        qw + ((size_t)b * 49 + qrow_a) * 128 + h * 16 + gq * 8);

  f32x4 s[13];
#pragma unroll
  for (int t = 0; t < 13; ++t) {
    bf16x8 bk = zero8();
    int n = t * 16 + l15;
    if (gq < 2 && n < 196)
      bk = *reinterpret_cast<const bf16x8*>(kvb + (size_t)n * 384 + gq * 8);
    s[t] = mfma_bf16(aq, bk, zero4());
  }

  const int qr = w_id * 16 + gq * 4;
#pragma unroll
  for (int t = 0; t < 13; ++t) {
    int n = t * 16 + l15;
#pragma unroll
    for (int r = 0; r < 4; ++r) {
      int q = qr + r;
      float val = -1e30f;
      if (n < 196) {
        float bias = (q < 49) ? ab[(size_t)(h * 49 + q) * 196 + n] : 0.f;
        val = s[t][r] * 0.25f + bias;
      }
      s[t][r] = val;
    }
  }

  float inv[4];
#pragma unroll
  for (int r = 0; r < 4; ++r) {
    float mx = s[0][r];
#pragma unroll
    for (int t = 1; t < 13; ++t) mx = fmaxf(mx, s[t][r]);
#pragma unroll
    for (int k = 1; k < 16; k <<= 1) mx = fmaxf(mx, __shfl_xor(mx, k, 64));
    float sum = 0.f;
#pragma unroll
    for (int t = 0; t < 13; ++t) {
      float e = __expf(s[t][r] - mx);
      s[t][r] = e;
      sum += e;
    }
#pragma unroll
    for (int k = 1; k < 16; k <<= 1) sum += __shfl_xor(sum, k, 64);
    inv[r] = 1.f / sum;
  }

#pragma unroll
  for (int t = 0; t < 13; ++t) {
    int n = t * 16 + l15;
#pragma unroll
    for (int r = 0; r < 4; ++r)
      pl[qr + r][n] = f2bf(s[t][r] * inv[r]);
  }
  __syncthreads();

  f32x4 o[2];
  o[0] = zero4(); o[1] = zero4();
  for (int c = 0; c < 7; ++c) {
    bf16x8 ap = *reinterpret_cast<const bf16x8*>(&pl[w_id * 16 + l15][c * 32 + gq * 8]);
#pragma unroll
    for (int nt = 0; nt < 2; ++nt) {
      bf16x8 bv = *reinterpret_cast<const bf16x8*>(&vt[nt * 16 + l15][c * 32 + gq * 8]);
      o[nt] = mfma_bf16(ap, bv, o[nt]);
    }
  }

#pragma unroll
  for (int nt = 0; nt < 2; ++nt) {
#pragma unroll
    for (int r = 0; r < 4; ++r) {
      int q = qr + r;
      if (q < 49) {
        float vv = o[nt][r];
        float hs = vv * fminf(fmaxf(vv + 3.f, 0.f), 6.f) * (1.f / 6.f);
        out[((size_t)b * 49 + q) * 256 + h * 32 + nt * 16 + l15] = f2bf(hs);
      }
    }
  }
}

// ---------------------------------------------------------------------------
// Kernel 4: out = at @ pk_p + bias -> f32 (B*49, 512). grid = 392*2 (N halves).
// ---------------------------------------------------------------------------
__global__ __launch_bounds__(256) void p_gemm2(
    const short* __restrict__ a_in, const short* __restrict__ pk,
    const float* __restrict__ bias, float* __restrict__ out) {
  __shared__ short bs[16 * 512];
  __shared__ float sb[256];
  const int tid = threadIdx.x, w_id = tid >> 6, lane = tid & 63;
  const int l15 = lane & 15, gq = lane >> 4;
  const int half = blockIdx.x & 1;
  const int mt = blockIdx.x >> 1;
  for (int i = tid; i < 256; i += 256) sb[i] = bias[half * 256 + i];
  const int arow = mt * 64 + w_id * 16 + l15;
  const short* arp = a_in + (size_t)arow * 256;

  f32x4 acc[16];
#pragma unroll
  for (int j = 0; j < 16; ++j) acc[j] = zero4();

  for (int c = 0; c < 8; ++c) {
    for (int seg = w_id; seg < 16; seg += 4)
      gload_lds16(pk + ((size_t)(c * 32 + half * 16 + seg) * 64 + lane) * 8,
                  &bs[seg * 512]);
    bf16x8 a = *reinterpret_cast<const bf16x8*>(arp + c * 32 + gq * 8);
    __syncthreads();
#pragma unroll
    for (int j = 0; j < 16; ++j) {
      bf16x8 bj = *reinterpret_cast<const bf16x8*>(&bs[(j * 64 + lane) * 8]);
      acc[j] = mfma_bf16(a, bj, acc[j]);
    }
    __syncthreads();
  }
  const int orow = mt * 64 + w_id * 16 + gq * 4;
#pragma unroll
  for (int j = 0; j < 16; ++j) {
    int chl = j * 16 + l15;
    float bb = sb[chl];
    int och = half * 256 + chl;
#pragma unroll
    for (int r = 0; r < 4; ++r)
      out[(size_t)(orow + r) * 512 + och] = acc[j][r] + bb;
  }
}

// ---------------------------------------------------------------------------
extern "C" void kernel_launch(void* const* d_in, const int* in_sizes, int n_in,
                              void* d_out, int out_size, void* d_ws, size_t ws_size,
                              hipStream_t stream) {
  const float* x    = (const float*)d_in[0];
  const float* w_kv = (const float*)d_in[1];
  const float* kv_g = (const float*)d_in[2];
  const float* kv_b = (const float*)d_in[3];
  const float* kv_m = (const float*)d_in[4];
  const float* kv_v = (const float*)d_in[5];
  const float* w_q  = (const float*)d_in[6];
  const float* q_g  = (const float*)d_in[7];
  const float* q_b  = (const float*)d_in[8];
  const float* q_m  = (const float*)d_in[9];
  const float* q_v  = (const float*)d_in[10];
  const float* w_p  = (const float*)d_in[11];
  const float* p_g  = (const float*)d_in[12];
  const float* p_b  = (const float*)d_in[13];
  const float* p_m  = (const float*)d_in[14];
  const float* p_v  = (const float*)d_in[15];
  const float* ab_t = (const float*)d_in[16];
  const int*   idxs = (const int*)d_in[17];
  const int n_off = in_sizes[16] / 8;

  char* ws = (char*)d_ws;
  short* pk_kv  = (short*)(ws);                    // 196,608
  short* pk_q   = (short*)(ws + 196608);           //  65,536
  short* pk_p   = (short*)(ws + 262144);           // 262,144
  float* bs_kv  = (float*)(ws + 524288);           //   1,536
  float* bs_q   = (float*)(ws + 525824);           //     512
  float* bs_p   = (float*)(ws + 526336);           //   2,048
  float* ab_ws  = (float*)(ws + 528384);           // 307,328
  short* kv_ws  = (short*)(ws + 835712);           // 77,070,336
  short* q_ws   = (short*)(ws + 77906048);         //  6,422,528
  short* at_ws  = (short*)(ws + 84328576);         // 12,845,056 -> 97,173,632

  pack_w_k<<<dim3(48), dim3(256), 0, stream>>>(w_kv, kv_g, kv_b, kv_m, kv_v, pk_kv, bs_kv, 384);
  pack_w_k<<<dim3(16), dim3(256), 0, stream>>>(w_q, q_g, q_b, q_m, q_v, pk_q, bs_q, 128);
  pack_w_k<<<dim3(64), dim3(256), 0, stream>>>(w_p, p_g, p_b, p_m, p_v, pk_p, bs_p, 512);
  ab_gather_k<<<dim3(392), dim3(256), 0, stream>>>(ab_t, idxs, ab_ws, n_off);

  kv_gemm2<<<dim3(1568), dim3(256), 0, stream>>>(x, pk_kv, bs_kv, kv_ws);
  q_gemm2<<<dim3(392), dim3(256), 0, stream>>>(x, pk_q, bs_q, q_ws);
  attn_k<<<dim3(4096), dim3(256), 0, stream>>>(kv_ws, q_ws, ab_ws, at_ws);
  p_gemm2<<<dim3(784), dim3(256), 0, stream>>>(at_ws, pk_p, bs_p, (float*)d_out);
}

// Round 3
// 175.543 us; speedup vs baseline: 1.3982x; 1.0969x over previous
//
#include <hip/hip_runtime.h>

typedef __attribute__((ext_vector_type(8))) short bf16x8;
typedef __attribute__((ext_vector_type(4))) float f32x4;
typedef __attribute__((ext_vector_type(4))) short short4v;
typedef __attribute__((ext_vector_type(4))) unsigned int u32x4;

#define DEVFN static __device__ __forceinline__

DEVFN short f2bf(float f) {
  unsigned int u = __builtin_bit_cast(unsigned int, f);
  unsigned int r = (u + 0x7FFFu + ((u >> 16) & 1u)) >> 16;   // RNE
  return (short)r;
}

DEVFN unsigned int pack2bf(float a, float b) {
  unsigned int lo = (unsigned int)(unsigned short)f2bf(a);
  unsigned int hi = (unsigned int)(unsigned short)f2bf(b);
  return lo | (hi << 16);
}

DEVFN f32x4 mfma_bf16(bf16x8 a, bf16x8 b, f32x4 c) {
  return __builtin_amdgcn_mfma_f32_16x16x32_bf16(a, b, c, 0, 0, 0);
}

DEVFN bf16x8 cvt8(const float* __restrict__ p) {
  const float4 u0 = *reinterpret_cast<const float4*>(p);
  const float4 u1 = *reinterpret_cast<const float4*>(p + 4);
  bf16x8 r;
  r[0] = f2bf(u0.x); r[1] = f2bf(u0.y); r[2] = f2bf(u0.z); r[3] = f2bf(u0.w);
  r[4] = f2bf(u1.x); r[5] = f2bf(u1.y); r[6] = f2bf(u1.z); r[7] = f2bf(u1.w);
  return r;
}

DEVFN f32x4 zero4() { f32x4 z = {0.f, 0.f, 0.f, 0.f}; return z; }
DEVFN bf16x8 zero8() { bf16x8 z = {0,0,0,0,0,0,0,0}; return z; }

DEVFN void gload_lds16(const void* g, void* l) {
  __builtin_amdgcn_global_load_lds(
      (const __attribute__((address_space(1))) unsigned int*)g,
      (__attribute__((address_space(3))) unsigned int*)l, 16, 0, 0);
}

// ---------------------------------------------------------------------------
// Weight pack: fold BN scale, cvt bf16, fragment-major layout
// ---------------------------------------------------------------------------
__global__ void pack_w_k(const float* __restrict__ w, const float* __restrict__ g,
                         const float* __restrict__ b, const float* __restrict__ m,
                         const float* __restrict__ v, short* __restrict__ pk,
                         float* __restrict__ bias, int O) {
  const int t = blockIdx.x * 256 + threadIdx.x;
  const int nt = O >> 4;
  const int total = nt * 8 * 64;
  if (t < total) {
    int lane = t & 63;
    int j = (t >> 6) % nt;
    int c = (t >> 6) / nt;
    int row = j * 16 + (lane & 15);
    int col = c * 32 + (lane >> 4) * 8;
    float s = g[row] * rsqrtf(v[row] + 1e-5f);
    const float* wp = w + (size_t)row * 256 + col;
    short* o = pk + (size_t)t * 8;
#pragma unroll
    for (int e = 0; e < 8; ++e) o[e] = f2bf(wp[e] * s);
  }
  if (t < O) {
    float s = g[t] * rsqrtf(v[t] + 1e-5f);
    bias[t] = b[t] - m[t] * s;
  }
}

// ---------------------------------------------------------------------------
// Kernel 1: kv = x @ pk_kv + bias -> bf16 (B*196, 384)
// ---------------------------------------------------------------------------
__global__ __launch_bounds__(256) void kv_gemm2(
    const float* __restrict__ x, const short* __restrict__ pk,
    const float* __restrict__ bias, short* __restrict__ out) {
  __shared__ short bs[24 * 512];
  __shared__ float sb[384];
  const int tid = threadIdx.x, w_id = tid >> 6, lane = tid & 63;
  const int l15 = lane & 15, gq = lane >> 4;
  const int mt = blockIdx.x;
  for (int i = tid; i < 384; i += 256) sb[i] = bias[i];
  const int arow = mt * 64 + w_id * 16 + l15;
  const float* xrow = x + (size_t)arow * 256;

  f32x4 acc[24];
#pragma unroll
  for (int j = 0; j < 24; ++j) acc[j] = zero4();

  for (int c = 0; c < 8; ++c) {
    for (int seg = w_id; seg < 24; seg += 4)
      gload_lds16(pk + ((size_t)(c * 24 + seg) * 64 + lane) * 8, &bs[seg * 512]);
    bf16x8 a = cvt8(xrow + c * 32 + gq * 8);
    __syncthreads();
#pragma unroll
    for (int j = 0; j < 24; ++j) {
      bf16x8 bj = *reinterpret_cast<const bf16x8*>(&bs[(j * 64 + lane) * 8]);
      acc[j] = mfma_bf16(a, bj, acc[j]);
    }
    __syncthreads();
  }
  const int orow = mt * 64 + w_id * 16 + gq * 4;
#pragma unroll
  for (int j = 0; j < 24; ++j) {
    int och = j * 16 + l15;
    float bb = sb[och];
#pragma unroll
    for (int r = 0; r < 4; ++r)
      out[(size_t)(orow + r) * 384 + och] = f2bf(acc[j][r] + bb);
  }
}

// ---------------------------------------------------------------------------
// Kernel 2: q = xs @ pk_q + bias -> bf16 (B*49, 128)
// ---------------------------------------------------------------------------
__global__ __launch_bounds__(256) void q_gemm2(
    const float* __restrict__ x, const short* __restrict__ pk,
    const float* __restrict__ bias, short* __restrict__ out) {
  __shared__ short bs[8 * 512];
  __shared__ float sb[128];
  const int tid = threadIdx.x, w_id = tid >> 6, lane = tid & 63;
  const int l15 = lane & 15, gq = lane >> 4;
  const int mt = blockIdx.x;
  if (tid < 128) sb[tid] = bias[tid];
  const int arow = mt * 64 + w_id * 16 + l15;
  const int b = arow / 49, qi = arow % 49;
  const int n = 28 * (qi / 7) + 2 * (qi % 7);
  const float* xrow = x + ((size_t)b * 196 + n) * 256;

  f32x4 acc[8];
#pragma unroll
  for (int j = 0; j < 8; ++j) acc[j] = zero4();

  for (int c = 0; c < 8; ++c) {
    for (int seg = w_id; seg < 8; seg += 4)
      gload_lds16(pk + ((size_t)(c * 8 + seg) * 64 + lane) * 8, &bs[seg * 512]);
    bf16x8 a = cvt8(xrow + c * 32 + gq * 8);
    __syncthreads();
#pragma unroll
    for (int j = 0; j < 8; ++j) {
      bf16x8 bj = *reinterpret_cast<const bf16x8*>(&bs[(j * 64 + lane) * 8]);
      acc[j] = mfma_bf16(a, bj, acc[j]);
    }
    __syncthreads();
  }
  const int orow = mt * 64 + w_id * 16 + gq * 4;
#pragma unroll
  for (int j = 0; j < 8; ++j) {
    int ch = j * 16 + l15;
    float bb = sb[ch];
#pragma unroll
    for (int r = 0; r < 4; ++r)
      out[(size_t)(orow + r) * 128 + ch] = f2bf(acc[j][r] + bb);
  }
}

// ---------------------------------------------------------------------------
// Kernel 2b: ab_full[h][q][n] = ab_table[h][bias_idxs[q][n]]
// ---------------------------------------------------------------------------
__global__ void ab_gather_k(const float* __restrict__ tab,
                            const int* __restrict__ idxs,
                            float* __restrict__ out, int n_off) {
  const int hq = blockIdx.x;
  const int h = hq / 49, q = hq % 49;
  const int t = threadIdx.x;
  if (t < 196)
    out[(size_t)hq * 196 + t] = tab[h * n_off + idxs[q * 196 + t]];
}

// ---------------------------------------------------------------------------
// Kernel 3 (NEW): swapped-operand attention, P kept entirely in registers.
// S[n][q] = mfma(K_tile, Q^T); tile t covers n = (t>>1)*32 + g*8 + (t&1)*4 + r
// so PV B-frags are lane-local register packs. Only V^T lives in LDS.
// grid = 4096 (b,h), 256 thr (4 waves = 4 q-tiles).
// ---------------------------------------------------------------------------
__global__ __launch_bounds__(256) void attn2_k(
    const short* __restrict__ kv, const short* __restrict__ qw,
    const float* __restrict__ ab, short* __restrict__ out) {
  __shared__ short vt[32][232];   // V^T [d][n], stride 232 (29 x 16B slots, odd)
  const int b = blockIdx.x >> 3, h = blockIdx.x & 7;
  const int tid = threadIdx.x;
  const int w_id = tid >> 6, lane = tid & 63;
  const int l15 = lane & 15, g = lane >> 4;

  // zero only pad cols 196..231 (dword writes)
  for (int i = tid; i < 32 * 18; i += 256) {
    int row = i / 18, cd = i - row * 18;
    *reinterpret_cast<unsigned int*>(&vt[row][196 + cd * 2]) = 0u;
  }
  const short* kvb = kv + ((size_t)b * 196) * 384 + h * 48;
  // stage V^T (consumed after the single barrier below)
  for (int i = tid; i < 196 * 32; i += 256) {
    int n = i >> 5, d = i & 31;
    vt[d][n] = kvb[(size_t)n * 384 + 16 + d];
  }

  const int q = w_id * 16 + l15;
  const bool qok = q < 49;
  bf16x8 bq = zero8();   // Q^T B-frag: col=q(l15), k=kd(g*8+e), kd>=16 zero
  if (g < 2 && qok)
    bq = *reinterpret_cast<const bf16x8*>(
        qw + ((size_t)b * 49 + q) * 128 + h * 16 + g * 8);

  // QK^T swapped: 13 tiles (tile 13 fully masked -> skipped)
  f32x4 s[13];
#pragma unroll
  for (int t = 0; t < 13; ++t) {
    int n_a = (t >> 1) * 32 + (l15 >> 2) * 8 + (t & 1) * 4 + (l15 & 3);
    bf16x8 ak = zero8();   // K A-frag: row=n-slot(l15), k=kd
    if (g < 2 && n_a < 196)
      ak = *reinterpret_cast<const bf16x8*>(kvb + (size_t)n_a * 384 + g * 8);
    s[t] = mfma_bf16(ak, bq, zero4());
  }

  // logits = s*SCALE + bias[q][n]; lane holds n = nb + r
  const float* abrow = ab + ((size_t)h * 49 + (qok ? q : 0)) * 196;
#pragma unroll
  for (int t = 0; t < 13; ++t) {
    int nb = (t >> 1) * 32 + g * 8 + (t & 1) * 4;
    if (nb < 196) {
      const float4 bi = *reinterpret_cast<const float4*>(abrow + nb);
      s[t][0] = s[t][0] * 0.25f + bi.x;
      s[t][1] = s[t][1] * 0.25f + bi.y;
      s[t][2] = s[t][2] * 0.25f + bi.z;
      s[t][3] = s[t][3] * 0.25f + bi.w;
    } else {
      s[t][0] = -1e30f; s[t][1] = -1e30f; s[t][2] = -1e30f; s[t][3] = -1e30f;
    }
  }

  // softmax over n for fixed q: local (t,r) + cross-group shfl (xor 16,32)
  float mx = s[0][0];
#pragma unroll
  for (int t = 0; t < 13; ++t) {
    mx = fmaxf(mx, fmaxf(fmaxf(s[t][0], s[t][1]), fmaxf(s[t][2], s[t][3])));
  }
  mx = fmaxf(mx, __shfl_xor(mx, 16, 64));
  mx = fmaxf(mx, __shfl_xor(mx, 32, 64));
  float sum = 0.f;
#pragma unroll
  for (int t = 0; t < 13; ++t) {
#pragma unroll
    for (int r = 0; r < 4; ++r) {
      float e = __expf(s[t][r] - mx);
      s[t][r] = e;
      sum += e;
    }
  }
  sum += __shfl_xor(sum, 16, 64);
  sum += __shfl_xor(sum, 32, 64);
  const float inv = 1.f / sum;

  // pack P to bf16 pairs (lane-local)
  unsigned int pk[14][2];
#pragma unroll
  for (int t = 0; t < 13; ++t) {
    pk[t][0] = pack2bf(s[t][0] * inv, s[t][1] * inv);
    pk[t][1] = pack2bf(s[t][2] * inv, s[t][3] * inv);
  }
  pk[13][0] = 0u; pk[13][1] = 0u;

  __syncthreads();   // V^T staged

  // PV swapped: O^T[d][q] = sum_n V^T[d][n] * P[n][q]
  f32x4 o0 = zero4(), o1 = zero4();
#pragma unroll
  for (int c = 0; c < 7; ++c) {
    u32x4 bp_u;
    bp_u[0] = pk[2 * c][0];     bp_u[1] = pk[2 * c][1];
    bp_u[2] = pk[2 * c + 1][0]; bp_u[3] = pk[2 * c + 1][1];
    bf16x8 bp = __builtin_bit_cast(bf16x8, bp_u);
    bf16x8 a0 = *reinterpret_cast<const bf16x8*>(&vt[l15][c * 32 + g * 8]);
    bf16x8 a1 = *reinterpret_cast<const bf16x8*>(&vt[16 + l15][c * 32 + g * 8]);
    o0 = mfma_bf16(a0, bp, o0);
    o1 = mfma_bf16(a1, bp, o1);
  }

  // epilogue: lane holds d = dt*16 + g*4 + r, q = l15 -> contiguous b64 stores
  if (qok) {
    short* op = out + (((size_t)b * 49 + q) * 256 + h * 32 + g * 4);
    short4v v0, v1;
#pragma unroll
    for (int r = 0; r < 4; ++r) {
      float x0 = o0[r];
      v0[r] = f2bf(x0 * fminf(fmaxf(x0 + 3.f, 0.f), 6.f) * (1.f / 6.f));
      float x1 = o1[r];
      v1[r] = f2bf(x1 * fminf(fmaxf(x1 + 3.f, 0.f), 6.f) * (1.f / 6.f));
    }
    *reinterpret_cast<short4v*>(op) = v0;
    *reinterpret_cast<short4v*>(op + 16) = v1;
  }
}

// ---------------------------------------------------------------------------
// Kernel 4: out = at @ pk_p + bias -> f32 (B*49, 512)
// ---------------------------------------------------------------------------
__global__ __launch_bounds__(256) void p_gemm2(
    const short* __restrict__ a_in, const short* __restrict__ pk,
    const float* __restrict__ bias, float* __restrict__ out) {
  __shared__ short bs[16 * 512];
  __shared__ float sb[256];
  const int tid = threadIdx.x, w_id = tid >> 6, lane = tid & 63;
  const int l15 = lane & 15, gq = lane >> 4;
  const int half = blockIdx.x & 1;
  const int mt = blockIdx.x >> 1;
  for (int i = tid; i < 256; i += 256) sb[i] = bias[half * 256 + i];
  const int arow = mt * 64 + w_id * 16 + l15;
  const short* arp = a_in + (size_t)arow * 256;

  f32x4 acc[16];
#pragma unroll
  for (int j = 0; j < 16; ++j) acc[j] = zero4();

  for (int c = 0; c < 8; ++c) {
    for (int seg = w_id; seg < 16; seg += 4)
      gload_lds16(pk + ((size_t)(c * 32 + half * 16 + seg) * 64 + lane) * 8,
                  &bs[seg * 512]);
    bf16x8 a = *reinterpret_cast<const bf16x8*>(arp + c * 32 + gq * 8);
    __syncthreads();
#pragma unroll
    for (int j = 0; j < 16; ++j) {
      bf16x8 bj = *reinterpret_cast<const bf16x8*>(&bs[(j * 64 + lane) * 8]);
      acc[j] = mfma_bf16(a, bj, acc[j]);
    }
    __syncthreads();
  }
  const int orow = mt * 64 + w_id * 16 + gq * 4;
#pragma unroll
  for (int j = 0; j < 16; ++j) {
    int chl = j * 16 + l15;
    float bb = sb[chl];
    int och = half * 256 + chl;
#pragma unroll
    for (int r = 0; r < 4; ++r)
      out[(size_t)(orow + r) * 512 + och] = acc[j][r] + bb;
  }
}

// ---------------------------------------------------------------------------
extern "C" void kernel_launch(void* const* d_in, const int* in_sizes, int n_in,
                              void* d_out, int out_size, void* d_ws, size_t ws_size,
                              hipStream_t stream) {
  const float* x    = (const float*)d_in[0];
  const float* w_kv = (const float*)d_in[1];
  const float* kv_g = (const float*)d_in[2];
  const float* kv_b = (const float*)d_in[3];
  const float* kv_m = (const float*)d_in[4];
  const float* kv_v = (const float*)d_in[5];
  const float* w_q  = (const float*)d_in[6];
  const float* q_g  = (const float*)d_in[7];
  const float* q_b  = (const float*)d_in[8];
  const float* q_m  = (const float*)d_in[9];
  const float* q_v  = (const float*)d_in[10];
  const float* w_p  = (const float*)d_in[11];
  const float* p_g  = (const float*)d_in[12];
  const float* p_b  = (const float*)d_in[13];
  const float* p_m  = (const float*)d_in[14];
  const float* p_v  = (const float*)d_in[15];
  const float* ab_t = (const float*)d_in[16];
  const int*   idxs = (const int*)d_in[17];
  const int n_off = in_sizes[16] / 8;

  char* ws = (char*)d_ws;
  short* pk_kv  = (short*)(ws);                    // 196,608
  short* pk_q   = (short*)(ws + 196608);           //  65,536
  short* pk_p   = (short*)(ws + 262144);           // 262,144
  float* bs_kv  = (float*)(ws + 524288);           //   1,536
  float* bs_q   = (float*)(ws + 525824);           //     512
  float* bs_p   = (float*)(ws + 526336);           //   2,048
  float* ab_ws  = (float*)(ws + 528384);           // 307,328
  short* kv_ws  = (short*)(ws + 835712);           // 77,070,336
  short* q_ws   = (short*)(ws + 77906048);         //  6,422,528
  short* at_ws  = (short*)(ws + 84328576);         // 12,845,056

  pack_w_k<<<dim3(48), dim3(256), 0, stream>>>(w_kv, kv_g, kv_b, kv_m, kv_v, pk_kv, bs_kv, 384);
  pack_w_k<<<dim3(16), dim3(256), 0, stream>>>(w_q, q_g, q_b, q_m, q_v, pk_q, bs_q, 128);
  pack_w_k<<<dim3(64), dim3(256), 0, stream>>>(w_p, p_g, p_b, p_m, p_v, pk_p, bs_p, 512);
  ab_gather_k<<<dim3(392), dim3(256), 0, stream>>>(ab_t, idxs, ab_ws, n_off);

  kv_gemm2<<<dim3(1568), dim3(256), 0, stream>>>(x, pk_kv, bs_kv, kv_ws);
  q_gemm2<<<dim3(392), dim3(256), 0, stream>>>(x, pk_q, bs_q, q_ws);
  attn2_k<<<dim3(4096), dim3(256), 0, stream>>>(kv_ws, q_ws, ab_ws, at_ws);
  p_gemm2<<<dim3(784), dim3(256), 0, stream>>>(at_ws, pk_p, bs_p, (float*)d_out);
}

// Round 4
// 159.398 us; speedup vs baseline: 1.5399x; 1.1013x over previous
//
#include <hip/hip_runtime.h>

typedef __attribute__((ext_vector_type(8))) short bf16x8;
typedef __attribute__((ext_vector_type(4))) float f32x4;
typedef __attribute__((ext_vector_type(4))) short short4v;
typedef __attribute__((ext_vector_type(4))) unsigned int u32x4;

#define DEVFN static __device__ __forceinline__

DEVFN short f2bf(float f) {
  unsigned int u = __builtin_bit_cast(unsigned int, f);
  unsigned int r = (u + 0x7FFFu + ((u >> 16) & 1u)) >> 16;   // RNE
  return (short)r;
}

DEVFN unsigned int pack2bf(float a, float b) {
  unsigned int lo = (unsigned int)(unsigned short)f2bf(a);
  unsigned int hi = (unsigned int)(unsigned short)f2bf(b);
  return lo | (hi << 16);
}

DEVFN f32x4 mfma_bf16(bf16x8 a, bf16x8 b, f32x4 c) {
  return __builtin_amdgcn_mfma_f32_16x16x32_bf16(a, b, c, 0, 0, 0);
}

DEVFN f32x4 zero4() { f32x4 z = {0.f, 0.f, 0.f, 0.f}; return z; }
DEVFN bf16x8 zero8() { bf16x8 z = {0,0,0,0,0,0,0,0}; return z; }

DEVFN void gload_lds16(const void* g, void* l) {
  __builtin_amdgcn_global_load_lds(
      (const __attribute__((address_space(1))) unsigned int*)g,
      (__attribute__((address_space(3))) unsigned int*)l, 16, 0, 0);
}

// 8-byte-aligned LDS load of 8 bf16 (avoids ds_read_b128 alignment assumption)
DEVFN bf16x8 lds8(const short* p) {
  short4v lo = *reinterpret_cast<const short4v*>(p);
  short4v hi = *reinterpret_cast<const short4v*>(p + 4);
  bf16x8 r;
  r[0] = lo[0]; r[1] = lo[1]; r[2] = lo[2]; r[3] = lo[3];
  r[4] = hi[0]; r[5] = hi[1]; r[6] = hi[2]; r[7] = hi[3];
  return r;
}

// ---------------------------------------------------------------------------
// Weight pack: fold BN scale, cvt bf16, fragment-major layout
// ---------------------------------------------------------------------------
__global__ void pack_w_k(const float* __restrict__ w, const float* __restrict__ g,
                         const float* __restrict__ b, const float* __restrict__ m,
                         const float* __restrict__ v, short* __restrict__ pk,
                         float* __restrict__ bias, int O) {
  const int t = blockIdx.x * 256 + threadIdx.x;
  const int nt = O >> 4;
  const int total = nt * 8 * 64;
  if (t < total) {
    int lane = t & 63;
    int j = (t >> 6) % nt;
    int c = (t >> 6) / nt;
    int row = j * 16 + (lane & 15);
    int col = c * 32 + (lane >> 4) * 8;
    float s = g[row] * rsqrtf(v[row] + 1e-5f);
    const float* wp = w + (size_t)row * 256 + col;
    short* o = pk + (size_t)t * 8;
#pragma unroll
    for (int e = 0; e < 8; ++e) o[e] = f2bf(wp[e] * s);
  }
  if (t < O) {
    float s = g[t] * rsqrtf(v[t] + 1e-5f);
    bias[t] = b[t] - m[t] * s;
  }
}

// ---------------------------------------------------------------------------
// Kernel 1: kv = x @ pk_kv + bias. 2-deep pipelined (dbuf LDS + x reg prefetch,
// counted vmcnt). Outputs K -> k_ws[b][h][196][16], V -> vT_ws[b][h][32][196].
// grid = 1568, 256 thr.
// ---------------------------------------------------------------------------
__global__ __launch_bounds__(256) void kv_gemm3(
    const float* __restrict__ x, const short* __restrict__ pk,
    const float* __restrict__ bias, short* __restrict__ k_out,
    short* __restrict__ vT_out) {
  __shared__ short bs[2][24 * 512];   // 2 x 24 KB
  __shared__ float sb[384];
  const int tid = threadIdx.x, w_id = tid >> 6, lane = tid & 63;
  const int l15 = lane & 15, g = lane >> 4;
  const int mt = blockIdx.x;
  for (int i = tid; i < 384; i += 256) sb[i] = bias[i];
  const int arow = mt * 64 + w_id * 16 + l15;
  const float* xrow = x + (size_t)arow * 256;

  f32x4 acc[24];
#pragma unroll
  for (int j = 0; j < 24; ++j) acc[j] = zero4();

#define STAGE_KV(buf, c)                                                      \
  for (int seg = w_id; seg < 24; seg += 4)                                    \
    gload_lds16(pk + ((size_t)((c) * 24 + seg) * 64 + lane) * 8,              \
                &bs[buf][seg * 512]);

  float4 xa[2], xb[2];
  STAGE_KV(0, 0)
  xa[0] = *reinterpret_cast<const float4*>(xrow + 0 * 32 + g * 8);
  xb[0] = *reinterpret_cast<const float4*>(xrow + 0 * 32 + g * 8 + 4);
  STAGE_KV(1, 1)
  xa[1] = *reinterpret_cast<const float4*>(xrow + 1 * 32 + g * 8);
  xb[1] = *reinterpret_cast<const float4*>(xrow + 1 * 32 + g * 8 + 4);
  asm volatile("s_waitcnt vmcnt(8)" ::: "memory");
  __syncthreads();

#pragma unroll
  for (int c = 0; c < 8; ++c) {
    const int cb = c & 1;
    bf16x8 a;
    a[0] = f2bf(xa[cb].x); a[1] = f2bf(xa[cb].y);
    a[2] = f2bf(xa[cb].z); a[3] = f2bf(xa[cb].w);
    a[4] = f2bf(xb[cb].x); a[5] = f2bf(xb[cb].y);
    a[6] = f2bf(xb[cb].z); a[7] = f2bf(xb[cb].w);
#pragma unroll
    for (int j = 0; j < 24; ++j) {
      bf16x8 bj = *reinterpret_cast<const bf16x8*>(&bs[cb][(j * 64 + lane) * 8]);
      acc[j] = mfma_bf16(a, bj, acc[j]);
    }
    __syncthreads();                       // B1: all waves done reading bs[cb]
    if (c + 2 < 8) {
      STAGE_KV(cb, c + 2)
      xa[cb] = *reinterpret_cast<const float4*>(xrow + (c + 2) * 32 + g * 8);
      xb[cb] = *reinterpret_cast<const float4*>(xrow + (c + 2) * 32 + g * 8 + 4);
      asm volatile("s_waitcnt vmcnt(8)" ::: "memory");  // STAGE(c+1)+x(c+1) done
    } else if (c == 6) {
      asm volatile("s_waitcnt vmcnt(0)" ::: "memory");  // STAGE(7)+x(7) done
    }
    if (c < 7) __syncthreads();            // B2: staged tile visible to all
  }

  // epilogue: rows row0..row0+3 never straddle a batch (196 % 4 == 0)
  const int row0 = mt * 64 + w_id * 16 + g * 4;
  const int bb_ = row0 / 196, n0 = row0 % 196;
#pragma unroll
  for (int j = 0; j < 24; ++j) {
    const int h = j / 3, part = j % 3;
    const float bv = sb[j * 16 + l15];
    if (part == 0) {
      short* kp = k_out + ((size_t)(bb_ * 8 + h) * 196 + n0) * 16 + l15;
#pragma unroll
      for (int r = 0; r < 4; ++r) kp[r * 16] = f2bf(acc[j][r] + bv);
    } else {
      const int d = (part - 1) * 16 + l15;
      short4v sv;
#pragma unroll
      for (int r = 0; r < 4; ++r) sv[r] = f2bf(acc[j][r] + bv);
      *reinterpret_cast<short4v*>(
          vT_out + ((size_t)(bb_ * 8 + h) * 32 + d) * 196 + n0) = sv;
    }
  }
}

// ---------------------------------------------------------------------------
// Kernel 2: q = xs @ pk_q + bias -> bf16 (B*49, 128). grid = 392.
// ---------------------------------------------------------------------------
__global__ __launch_bounds__(256) void q_gemm2(
    const float* __restrict__ x, const short* __restrict__ pk,
    const float* __restrict__ bias, short* __restrict__ out) {
  __shared__ short bs[8 * 512];
  __shared__ float sb[128];
  const int tid = threadIdx.x, w_id = tid >> 6, lane = tid & 63;
  const int l15 = lane & 15, gq = lane >> 4;
  const int mt = blockIdx.x;
  if (tid < 128) sb[tid] = bias[tid];
  const int arow = mt * 64 + w_id * 16 + l15;
  const int b = arow / 49, qi = arow % 49;
  const int n = 28 * (qi / 7) + 2 * (qi % 7);
  const float* xrow = x + ((size_t)b * 196 + n) * 256;

  f32x4 acc[8];
#pragma unroll
  for (int j = 0; j < 8; ++j) acc[j] = zero4();

  for (int c = 0; c < 8; ++c) {
    for (int seg = w_id; seg < 8; seg += 4)
      gload_lds16(pk + ((size_t)(c * 8 + seg) * 64 + lane) * 8, &bs[seg * 512]);
    const float4 u0 = *reinterpret_cast<const float4*>(xrow + c * 32 + gq * 8);
    const float4 u1 = *reinterpret_cast<const float4*>(xrow + c * 32 + gq * 8 + 4);
    bf16x8 a;
    a[0] = f2bf(u0.x); a[1] = f2bf(u0.y); a[2] = f2bf(u0.z); a[3] = f2bf(u0.w);
    a[4] = f2bf(u1.x); a[5] = f2bf(u1.y); a[6] = f2bf(u1.z); a[7] = f2bf(u1.w);
    __syncthreads();
#pragma unroll
    for (int j = 0; j < 8; ++j) {
      bf16x8 bj = *reinterpret_cast<const bf16x8*>(&bs[(j * 64 + lane) * 8]);
      acc[j] = mfma_bf16(a, bj, acc[j]);
    }
    __syncthreads();
  }
  const int orow = mt * 64 + w_id * 16 + gq * 4;
#pragma unroll
  for (int j = 0; j < 8; ++j) {
    int ch = j * 16 + l15;
    float bb = sb[ch];
#pragma unroll
    for (int r = 0; r < 4; ++r)
      out[(size_t)(orow + r) * 128 + ch] = f2bf(acc[j][r] + bb);
  }
}

// ---------------------------------------------------------------------------
// Kernel 2b: ab_full[h][q][n] = ab_table[h][bias_idxs[q][n]]
// ---------------------------------------------------------------------------
__global__ void ab_gather_k(const float* __restrict__ tab,
                            const int* __restrict__ idxs,
                            float* __restrict__ out, int n_off) {
  const int hq = blockIdx.x;
  const int h = hq / 49, q = hq % 49;
  const int t = threadIdx.x;
  if (t < 196)
    out[(size_t)hq * 196 + t] = tab[h * n_off + idxs[q * 196 + t]];
}

// ---------------------------------------------------------------------------
// Kernel 3: swapped-operand attention; V^T slab gload_lds-staged, K from
// compact k_ws, P in registers. grid = 4096 (b,h), 256 thr.
// ---------------------------------------------------------------------------
__global__ __launch_bounds__(256) void attn3_k(
    const short* __restrict__ k_ws, const short* __restrict__ vT_ws,
    const short* __restrict__ qw, const float* __restrict__ ab,
    short* __restrict__ out) {
  __shared__ short vt[6304];   // [32][196] packed (12544 B) + 64 B guard
  const int b = blockIdx.x >> 3, h = blockIdx.x & 7;
  const int tid = threadIdx.x, w_id = tid >> 6, lane = tid & 63;
  const int l15 = lane & 15, g = lane >> 4;

  // zero guard (row-31 PV over-read spills here; must be finite)
  if (tid < 16) *reinterpret_cast<unsigned int*>(&vt[6272 + tid * 2]) = 0u;

  // stage V^T slab: 12544 B contiguous = 784 granules of 16 B
  const short* vsrc = vT_ws + (size_t)(b * 8 + h) * 6272;
  for (int s = w_id; s < 13; s += 4) {
    if (s * 64 + lane < 784)
      gload_lds16(vsrc + (size_t)(s * 64 + lane) * 8, &vt[s * 512]);
  }

  const short* kslab = k_ws + (size_t)(b * 8 + h) * 3136;   // [196][16]

  const int q = w_id * 16 + l15;
  const bool qok = q < 49;
  bf16x8 bq = zero8();
  if (g < 2 && qok)
    bq = *reinterpret_cast<const bf16x8*>(
        qw + ((size_t)b * 49 + q) * 128 + h * 16 + g * 8);

  // QK^T swapped, permuted n-mapping (lane-local PV B-frags)
  f32x4 s[13];
#pragma unroll
  for (int t = 0; t < 13; ++t) {
    int n_a = (t >> 1) * 32 + (l15 >> 2) * 8 + (t & 1) * 4 + (l15 & 3);
    bf16x8 ak = zero8();
    if (g < 2 && n_a < 196)
      ak = *reinterpret_cast<const bf16x8*>(kslab + (size_t)n_a * 16 + g * 8);
    s[t] = mfma_bf16(ak, bq, zero4());
  }

  const float* abrow = ab + ((size_t)h * 49 + (qok ? q : 0)) * 196;
#pragma unroll
  for (int t = 0; t < 13; ++t) {
    int nb = (t >> 1) * 32 + g * 8 + (t & 1) * 4;
    if (nb < 196) {
      const float4 bi = *reinterpret_cast<const float4*>(abrow + nb);
      s[t][0] = s[t][0] * 0.25f + bi.x;
      s[t][1] = s[t][1] * 0.25f + bi.y;
      s[t][2] = s[t][2] * 0.25f + bi.z;
      s[t][3] = s[t][3] * 0.25f + bi.w;
    } else {
      s[t][0] = -1e30f; s[t][1] = -1e30f; s[t][2] = -1e30f; s[t][3] = -1e30f;
    }
  }

  // softmax over n (local + xor16/32 across the 4 groups)
  float mx = s[0][0];
#pragma unroll
  for (int t = 0; t < 13; ++t)
    mx = fmaxf(mx, fmaxf(fmaxf(s[t][0], s[t][1]), fmaxf(s[t][2], s[t][3])));
  mx = fmaxf(mx, __shfl_xor(mx, 16, 64));
  mx = fmaxf(mx, __shfl_xor(mx, 32, 64));
  float sum = 0.f;
#pragma unroll
  for (int t = 0; t < 13; ++t) {
#pragma unroll
    for (int r = 0; r < 4; ++r) {
      float e = __expf(s[t][r] - mx);
      s[t][r] = e;
      sum += e;
    }
  }
  sum += __shfl_xor(sum, 16, 64);
  sum += __shfl_xor(sum, 32, 64);
  const float inv = 1.f / sum;

  unsigned int pkr[14][2];
#pragma unroll
  for (int t = 0; t < 13; ++t) {
    pkr[t][0] = pack2bf(s[t][0] * inv, s[t][1] * inv);
    pkr[t][1] = pack2bf(s[t][2] * inv, s[t][3] * inv);
  }
  pkr[13][0] = 0u; pkr[13][1] = 0u;

  __syncthreads();   // V^T staged (drains vmcnt+lgkmcnt)

  // PV swapped: O^T[d][q] = sum_n V^T[d][n] * P[n][q]
  f32x4 o0 = zero4(), o1 = zero4();
#pragma unroll
  for (int c = 0; c < 7; ++c) {
    u32x4 bp_u;
    bp_u[0] = pkr[2 * c][0];     bp_u[1] = pkr[2 * c][1];
    bp_u[2] = pkr[2 * c + 1][0]; bp_u[3] = pkr[2 * c + 1][1];
    bf16x8 bp = __builtin_bit_cast(bf16x8, bp_u);
    bf16x8 a0 = lds8(&vt[l15 * 196 + c * 32 + g * 8]);
    bf16x8 a1 = lds8(&vt[(16 + l15) * 196 + c * 32 + g * 8]);
    o0 = mfma_bf16(a0, bp, o0);
    o1 = mfma_bf16(a1, bp, o1);
  }

  if (qok) {
    short* op = out + (((size_t)b * 49 + q) * 256 + h * 32 + g * 4);
    short4v v0, v1;
#pragma unroll
    for (int r = 0; r < 4; ++r) {
      float x0 = o0[r];
      v0[r] = f2bf(x0 * fminf(fmaxf(x0 + 3.f, 0.f), 6.f) * (1.f / 6.f));
      float x1 = o1[r];
      v1[r] = f2bf(x1 * fminf(fmaxf(x1 + 3.f, 0.f), 6.f) * (1.f / 6.f));
    }
    *reinterpret_cast<short4v*>(op) = v0;
    *reinterpret_cast<short4v*>(op + 16) = v1;
  }
}

// ---------------------------------------------------------------------------
// Kernel 4: out = at @ pk_p + bias -> f32 (B*49, 512). grid = 392*2.
// ---------------------------------------------------------------------------
__global__ __launch_bounds__(256) void p_gemm2(
    const short* __restrict__ a_in, const short* __restrict__ pk,
    const float* __restrict__ bias, float* __restrict__ out) {
  __shared__ short bs[16 * 512];
  __shared__ float sb[256];
  const int tid = threadIdx.x, w_id = tid >> 6, lane = tid & 63;
  const int l15 = lane & 15, gq = lane >> 4;
  const int half = blockIdx.x & 1;
  const int mt = blockIdx.x >> 1;
  for (int i = tid; i < 256; i += 256) sb[i] = bias[half * 256 + i];
  const int arow = mt * 64 + w_id * 16 + l15;
  const short* arp = a_in + (size_t)arow * 256;

  f32x4 acc[16];
#pragma unroll
  for (int j = 0; j < 16; ++j) acc[j] = zero4();

  for (int c = 0; c < 8; ++c) {
    for (int seg = w_id; seg < 16; seg += 4)
      gload_lds16(pk + ((size_t)(c * 32 + half * 16 + seg) * 64 + lane) * 8,
                  &bs[seg * 512]);
    bf16x8 a = *reinterpret_cast<const bf16x8*>(arp + c * 32 + gq * 8);
    __syncthreads();
#pragma unroll
    for (int j = 0; j < 16; ++j) {
      bf16x8 bj = *reinterpret_cast<const bf16x8*>(&bs[(j * 64 + lane) * 8]);
      acc[j] = mfma_bf16(a, bj, acc[j]);
    }
    __syncthreads();
  }
  const int orow = mt * 64 + w_id * 16 + gq * 4;
#pragma unroll
  for (int j = 0; j < 16; ++j) {
    int chl = j * 16 + l15;
    float bb = sb[chl];
    int och = half * 256 + chl;
#pragma unroll
    for (int r = 0; r < 4; ++r)
      out[(size_t)(orow + r) * 512 + och] = acc[j][r] + bb;
  }
}

// ---------------------------------------------------------------------------
extern "C" void kernel_launch(void* const* d_in, const int* in_sizes, int n_in,
                              void* d_out, int out_size, void* d_ws, size_t ws_size,
                              hipStream_t stream) {
  const float* x    = (const float*)d_in[0];
  const float* w_kv = (const float*)d_in[1];
  const float* kv_g = (const float*)d_in[2];
  const float* kv_b = (const float*)d_in[3];
  const float* kv_m = (const float*)d_in[4];
  const float* kv_v = (const float*)d_in[5];
  const float* w_q  = (const float*)d_in[6];
  const float* q_g  = (const float*)d_in[7];
  const float* q_b  = (const float*)d_in[8];
  const float* q_m  = (const float*)d_in[9];
  const float* q_v  = (const float*)d_in[10];
  const float* w_p  = (const float*)d_in[11];
  const float* p_g  = (const float*)d_in[12];
  const float* p_b  = (const float*)d_in[13];
  const float* p_m  = (const float*)d_in[14];
  const float* p_v  = (const float*)d_in[15];
  const float* ab_t = (const float*)d_in[16];
  const int*   idxs = (const int*)d_in[17];
  const int n_off = in_sizes[16] / 8;

  char* ws = (char*)d_ws;
  short* pk_kv  = (short*)(ws);                    //    196,608
  short* pk_q   = (short*)(ws + 196608);           //     65,536
  short* pk_p   = (short*)(ws + 262144);           //    262,144
  float* bs_kv  = (float*)(ws + 524288);           //      1,536
  float* bs_q   = (float*)(ws + 525824);           //        512
  float* bs_p   = (float*)(ws + 526336);           //      2,048
  float* ab_ws  = (float*)(ws + 528384);           //    307,328 -> 835,712
  short* k_ws   = (short*)(ws + 835712);           // 25,690,112 -> 26,525,824
  short* vT_ws  = (short*)(ws + 26525824);         // 51,380,224 -> 77,906,048
  short* q_ws   = (short*)(ws + 77906048);         //  6,422,528 -> 84,328,576
  short* at_ws  = (short*)(ws + 84328576);         // 12,845,056 -> 97,173,632

  pack_w_k<<<dim3(48), dim3(256), 0, stream>>>(w_kv, kv_g, kv_b, kv_m, kv_v, pk_kv, bs_kv, 384);
  pack_w_k<<<dim3(16), dim3(256), 0, stream>>>(w_q, q_g, q_b, q_m, q_v, pk_q, bs_q, 128);
  pack_w_k<<<dim3(64), dim3(256), 0, stream>>>(w_p, p_g, p_b, p_m, p_v, pk_p, bs_p, 512);
  ab_gather_k<<<dim3(392), dim3(256), 0, stream>>>(ab_t, idxs, ab_ws, n_off);

  kv_gemm3<<<dim3(1568), dim3(256), 0, stream>>>(x, pk_kv, bs_kv, k_ws, vT_ws);
  q_gemm2<<<dim3(392), dim3(256), 0, stream>>>(x, pk_q, bs_q, q_ws);
  attn3_k<<<dim3(4096), dim3(256), 0, stream>>>(k_ws, vT_ws, q_ws, ab_ws, at_ws);
  p_gemm2<<<dim3(784), dim3(256), 0, stream>>>(at_ws, pk_p, bs_p, (float*)d_out);
}